// Round 1
// baseline (4235.999 us; speedup 1.0000x reference)
//
#include <hip/hip_runtime.h>
#include <math.h>

#define NB 32
#define NS 4096
#define ND 768
#define NH 1024
#define NTOK (NB*NS)

// ---------------------------------------------------------------------------
// Kernel A: LayerNorm statistics. One wave per token (4 tokens / 256-thr block).
// Two-pass (mean, then centered variance) for accuracy. Writes mu, rsigma.
// ---------------------------------------------------------------------------
__global__ __launch_bounds__(256) void k_lnstats(
    const float* __restrict__ emb, const float* __restrict__ attn,
    float* __restrict__ mu_o, float* __restrict__ rs_o)
{
    const int token = blockIdx.x * 4 + (threadIdx.x >> 6);
    const int lane  = threadIdx.x & 63;
    const float am  = attn[token];
    const float* row = emb + (size_t)token * ND;

    float e[12];
    float s = 0.f;
#pragma unroll
    for (int j = 0; j < 12; j++) { e[j] = row[lane + 64*j] * am; s += e[j]; }
#pragma unroll
    for (int m = 32; m; m >>= 1) s += __shfl_xor(s, m, 64);
    const float mu = s * (1.0f / ND);

    float v = 0.f;
#pragma unroll
    for (int j = 0; j < 12; j++) { float d = e[j] - mu; v += d * d; }
#pragma unroll
    for (int m = 32; m; m >>= 1) v += __shfl_xor(v, m, 64);
    v *= (1.0f / ND);

    if (lane == 0) {
        mu_o[token] = mu;
        rs_o[token] = (float)(1.0 / sqrt((double)v + 1e-5));
    }
}

// ---------------------------------------------------------------------------
// Kernel B: fused LN + MLP scorer. scores[t] = sum_h gelu(x_t . w1[h] + b1[h]) * w2[h] + b2
// 32-token tile / 256-thread WG. LDS: x chunk [32k][32t] (4KB) + w chunk
// [32k][512h] (64KB) = 68KB -> 2 WG/CU. Per-thread 8t x 8h register tile:
// 64 FMA per k vs 4 LDS instrs (2 broadcast b128 + 2 conflict-free b128).
// H processed as two 512-halves (acc regs), x restaged per half.
// ---------------------------------------------------------------------------
#define TM 32
#define KC 32

__global__ __launch_bounds__(256, 2) void k_scorer(
    const float* __restrict__ emb, const float* __restrict__ attn,
    const float* __restrict__ ln_g, const float* __restrict__ ln_b,
    const float* __restrict__ w1, const float* __restrict__ b1,
    const float* __restrict__ w2, const float* __restrict__ b2v,
    const float* __restrict__ mu_a, const float* __restrict__ rs_a,
    float* __restrict__ scores)
{
    __shared__ float xs[KC * TM];     // [k][t]   4 KB
    __shared__ float wsh[KC * 512];   // [k][h]  64 KB

    const int tid   = threadIdx.x;
    const int lane  = tid & 63;
    const int wv    = tid >> 6;       // wave id 0..3
    const int t0    = wv * 8;         // this wave's 8 tokens (local)
    const int token0 = blockIdx.x * TM;

    // staging assignment: thread covers token st_t, k-offsets st_k..st_k+3
    const int st_t = tid >> 3;        // 0..31
    const int st_k = (tid & 7) * 4;   // 0,4,...,28
    const float mu_t = mu_a[token0 + st_t];
    const float rs_t = rs_a[token0 + st_t];
    const float at_t = attn[token0 + st_t];

    float spart[8];
#pragma unroll
    for (int i = 0; i < 8; i++) spart[i] = 0.f;

    for (int hh = 0; hh < 2; hh++) {
        float acc[8][8];
#pragma unroll
        for (int i = 0; i < 8; i++)
#pragma unroll
            for (int j = 0; j < 8; j++) acc[i][j] = 0.f;

        for (int kc = 0; kc < ND; kc += KC) {
            __syncthreads();   // previous chunk fully consumed
            // ---- stage x (LN applied on the fly), transposed [k][t] ----
            {
                const float4 ev = *(const float4*)(emb + (size_t)(token0 + st_t) * ND + kc + st_k);
                const float4 gv = *(const float4*)(ln_g + kc + st_k);
                const float4 bv = *(const float4*)(ln_b + kc + st_k);
                xs[(st_k + 0) * TM + st_t] = (ev.x * at_t - mu_t) * rs_t * gv.x + bv.x;
                xs[(st_k + 1) * TM + st_t] = (ev.y * at_t - mu_t) * rs_t * gv.y + bv.y;
                xs[(st_k + 2) * TM + st_t] = (ev.z * at_t - mu_t) * rs_t * gv.z + bv.z;
                xs[(st_k + 3) * TM + st_t] = (ev.w * at_t - mu_t) * rs_t * gv.w + bv.w;
            }
            // ---- stage w1 chunk, transposed [k][h] ----
#pragma unroll
            for (int j = 0; j < 16; j++) {
                const int q  = tid + (j << 8);   // 0..4095 float4s
                const int h  = q >> 3;           // 0..511
                const int k4 = (q & 7) * 4;
                const float4 w4 = *(const float4*)(w1 + (size_t)(hh * 512 + h) * ND + kc + k4);
                wsh[(k4 + 0) * 512 + h] = w4.x;
                wsh[(k4 + 1) * 512 + h] = w4.y;
                wsh[(k4 + 2) * 512 + h] = w4.z;
                wsh[(k4 + 3) * 512 + h] = w4.w;
            }
            __syncthreads();
            // ---- inner product ----
#pragma unroll 8
            for (int k = 0; k < KC; k++) {
                const float4 xa = *(const float4*)&xs[k * TM + t0];      // broadcast
                const float4 xb = *(const float4*)&xs[k * TM + t0 + 4];  // broadcast
                const float4 wa = *(const float4*)&wsh[k * 512 + lane * 4];
                const float4 wb = *(const float4*)&wsh[k * 512 + 256 + lane * 4];
                const float xv[8]  = {xa.x, xa.y, xa.z, xa.w, xb.x, xb.y, xb.z, xb.w};
                const float wvv[8] = {wa.x, wa.y, wa.z, wa.w, wb.x, wb.y, wb.z, wb.w};
#pragma unroll
                for (int i = 0; i < 8; i++)
#pragma unroll
                    for (int j = 0; j < 8; j++)
                        acc[i][j] += xv[i] * wvv[j];
            }
        }
        // ---- epilogue for this half: gelu + w2 reduce into spart ----
        const int hA = hh * 512 + lane * 4;
#pragma unroll
        for (int j = 0; j < 8; j++) {
            const int hg = (j < 4) ? (hA + j) : (hA + 256 + (j - 4));
            const float b1v = b1[hg];
            const float w2h = w2[hg];
#pragma unroll
            for (int i = 0; i < 8; i++) {
                const float pre = acc[i][j] + b1v;
                const float ge  = 0.5f * pre * (1.0f + erff(pre * 0.70710678118654752f));
                spart[i] += ge * w2h;
            }
        }
    }
    // wave-reduce the 8 token partials over 64 h-lanes
#pragma unroll
    for (int i = 0; i < 8; i++) {
        float s = spart[i];
#pragma unroll
        for (int m = 32; m; m >>= 1) s += __shfl_xor(s, m, 64);
        spart[i] = s;
    }
    if (lane == 0) {
        const float bb = b2v[0];
#pragma unroll
        for (int i = 0; i < 8; i++) scores[token0 + t0 + i] = spart[i] + bb;
    }
}

// ---------------------------------------------------------------------------
// Kernel C: entmax1.5 over S per batch row (bisection for tau in fp64) +
// Kumaraswamy relaxed gate (fp64 elementwise) + outputs z, g, reg.
// One 1024-thread block per batch row; 4 elements/thread held in registers.
// ---------------------------------------------------------------------------
static __device__ __forceinline__ double softplus_d(double x) {
    return (x > 30.0) ? x : log1p(exp(x));
}

__global__ __launch_bounds__(1024) void k_entgate(
    const float* __restrict__ scores, const float* __restrict__ attn,
    const float* __restrict__ u, float* __restrict__ out)
{
    const int b    = blockIdx.x;
    const int tid  = threadIdx.x;
    const int lane = tid & 63;
    const int wid  = tid >> 6;

    __shared__ double redd[16];
    __shared__ double bcd;
    __shared__ float  redf[16];
    __shared__ float  bcf;

    float sm[4], at[4], vv[4];
#pragma unroll
    for (int j = 0; j < 4; j++) {
        const int i = tid + 1024 * j;
        at[j] = attn[b * NS + i];
        const float s = scores[b * NS + i];
        sm[j] = (at[j] == 0.0f) ? -1e9f : s;   // mask
        vv[j] = sm[j] * 0.5f;                  // x = (scores/TAU)/2, TAU=1
    }

    // block max of vv
    float mx = fmaxf(fmaxf(vv[0], vv[1]), fmaxf(vv[2], vv[3]));
#pragma unroll
    for (int m = 32; m; m >>= 1) mx = fmaxf(mx, __shfl_xor(mx, m, 64));
    if (lane == 0) redf[wid] = mx;
    __syncthreads();
    if (tid == 0) {
        float t = redf[0];
        for (int i = 1; i < 16; i++) t = fmaxf(t, redf[i]);
        bcf = t;
    }
    __syncthreads();
    const double mxd = (double)bcf;

    double d[4];
#pragma unroll
    for (int j = 0; j < 4; j++) d[j] = (double)vv[j] - mxd;

    // bisection: f(tau) = sum((d - tau)_+^2) = 1, monotone decreasing.
    // f(0) = 0 (< 1), f(-1) >= 1 (max element alone contributes 1).
    double lo = -1.0, hi = 0.0;
    for (int it = 0; it < 44; it++) {
        const double mid = 0.5 * (lo + hi);
        double s = 0.0;
#pragma unroll
        for (int j = 0; j < 4; j++) {
            const double t = d[j] - mid;
            if (t > 0.0) s += t * t;
        }
#pragma unroll
        for (int m = 32; m; m >>= 1) s += __shfl_xor(s, m, 64);
        if (lane == 0) redd[wid] = s;
        __syncthreads();
        if (tid == 0) {
            double t = 0.0;
            for (int i = 0; i < 16; i++) t += redd[i];
            bcd = t;
        }
        __syncthreads();
        if (bcd >= 1.0) lo = mid; else hi = mid;   // uniform branch
    }
    const double tau = lo;

    if (b == 0 && tid == 0) out[2 * NTOK] = 0.0f;  // reg = 0 (re-poisoned each call)

#pragma unroll
    for (int j = 0; j < 4; j++) {
        const int i = tid + 1024 * j;
        const double t  = d[j] - tau;
        const double zz = (t > 0.0) ? t * t : 0.0;
        const float  z  = (float)zz * at[j];

        // eff = scores + K*(2z - 1), K = 2
        const double eff  = (double)sm[j] + 2.0 * (2.0 * (double)z - 1.0);
        const double sp_p = softplus_d(eff)  + 1e-6;   // a
        const double sp_n = softplus_d(-eff) + 1e-6;   // b
        const double uc   = fmin(fmax((double)u[b * NS + i], 1e-6), 1.0 - 1e-6);
        const double xk   = pow(1.0 - pow(1.0 - uc, 1.0 / sp_n), 1.0 / sp_p);
        const double y    = -0.1 + 1.2 * xk;
        const double ycl  = fmin(fmax(y, 0.0), 1.0);
        float h = (ycl > 0.5) ? 1.0f : 0.0f;
        h *= at[j];
        const float g = (h - z) + z;   // straight-through forward value

        out[b * NS + i]        = z;
        out[NTOK + b * NS + i] = g;
    }
}

// ---------------------------------------------------------------------------
extern "C" void kernel_launch(void* const* d_in, const int* in_sizes, int n_in,
                              void* d_out, int out_size, void* d_ws, size_t ws_size,
                              hipStream_t stream)
{
    const float* emb  = (const float*)d_in[0];
    const float* attn = (const float*)d_in[1];
    const float* u    = (const float*)d_in[2];
    const float* ln_g = (const float*)d_in[3];
    const float* ln_b = (const float*)d_in[4];
    const float* w1   = (const float*)d_in[5];
    const float* b1   = (const float*)d_in[6];
    const float* w2   = (const float*)d_in[7];
    const float* b2   = (const float*)d_in[8];
    float* out = (float*)d_out;

    float* wsf    = (float*)d_ws;
    float* scores = wsf;              // NTOK floats
    float* mu     = wsf + NTOK;       // NTOK floats
    float* rs     = wsf + 2 * NTOK;   // NTOK floats  (total 1.5 MB of ws)

    hipLaunchKernelGGL(k_lnstats, dim3(NTOK / 4), dim3(256), 0, stream,
                       emb, attn, mu, rs);
    hipLaunchKernelGGL(k_scorer, dim3(NTOK / TM), dim3(256), 0, stream,
                       emb, attn, ln_g, ln_b, w1, b1, w2, b2, mu, rs, scores);
    hipLaunchKernelGGL(k_entgate, dim3(NB), dim3(1024), 0, stream,
                       scores, attn, u, out);
}

// Round 2
// 1632.061 us; speedup vs baseline: 2.5955x; 2.5955x over previous
//
#include <hip/hip_runtime.h>
#include <math.h>

#define NB 32
#define NS 4096
#define ND 768
#define NH 1024
#define NTOK (NB*NS)

typedef __bf16 bf16_t;
typedef __bf16 bf16x8 __attribute__((ext_vector_type(8)));
typedef __bf16 bf16x4 __attribute__((ext_vector_type(4)));
typedef float  f32x4  __attribute__((ext_vector_type(4)));

// ---------------------------------------------------------------------------
// Kernel A: LayerNorm statistics. One wave per token. Writes mu, rsigma.
// ---------------------------------------------------------------------------
__global__ __launch_bounds__(256) void k_lnstats(
    const float* __restrict__ emb, const float* __restrict__ attn,
    float* __restrict__ mu_o, float* __restrict__ rs_o)
{
    const int token = blockIdx.x * 4 + (threadIdx.x >> 6);
    const int lane  = threadIdx.x & 63;
    const float am  = attn[token];
    const float* row = emb + (size_t)token * ND;

    float e[12];
    float s = 0.f;
#pragma unroll
    for (int j = 0; j < 12; j++) { e[j] = row[lane + 64*j] * am; s += e[j]; }
#pragma unroll
    for (int m = 32; m; m >>= 1) s += __shfl_xor(s, m, 64);
    const float mu = s * (1.0f / ND);

    float v = 0.f;
#pragma unroll
    for (int j = 0; j < 12; j++) { float d = e[j] - mu; v += d * d; }
#pragma unroll
    for (int m = 32; m; m >>= 1) v += __shfl_xor(v, m, 64);
    v *= (1.0f / ND);

    if (lane == 0) {
        mu_o[token] = mu;
        rs_o[token] = (float)(1.0 / sqrt((double)v + 1e-5));
    }
}

// ---------------------------------------------------------------------------
// Kernel P: split w1 (fp32 [H][D]) into bf16 hi/lo, same [h][k] layout.
// ---------------------------------------------------------------------------
__global__ __launch_bounds__(256) void k_wsplit(
    const float* __restrict__ w1, bf16_t* __restrict__ wh, bf16_t* __restrict__ wl)
{
    const int i = (blockIdx.x * 256 + threadIdx.x) * 4;
    const float4 v = *(const float4*)(w1 + i);
    const float vv[4] = {v.x, v.y, v.z, v.w};
    bf16x4 h, l;
#pragma unroll
    for (int j = 0; j < 4; j++) {
        const bf16_t hj = (bf16_t)vv[j];
        h[j] = hj;
        l[j] = (bf16_t)(vv[j] - (float)hj);
    }
    *(bf16x4*)(wh + i) = h;
    *(bf16x4*)(wl + i) = l;
}

// ---------------------------------------------------------------------------
// Kernel B: fused LN + MLP scorer via bf16x3-split MFMA (16x16x32).
// TM=64 tokens/WG, H in two 512-halves, KC=32. 4 waves x (4 t-tiles x 8 h-tiles).
// W staged by global_load_lds width=16 (no VGPR round trip); X staged through
// VGPRs with LN+hi/lo split fused. XOR swizzle (k-block q ^ ((row>>2)&3))
// => conflict-free fragment reads AND staging writes, zero padding.
// LDS: Wh 32K + Wl 32K + Xh 4K + Xl 4K + sred 1K = 73 KB -> 2 WG/CU.
// ---------------------------------------------------------------------------
#define TM 64
#define KC 32

__global__ __launch_bounds__(256, 2) void k_scorer(
    const float* __restrict__ emb, const float* __restrict__ attn,
    const float* __restrict__ ln_g, const float* __restrict__ ln_b,
    const bf16_t* __restrict__ w1h, const bf16_t* __restrict__ w1l,
    const float* __restrict__ b1, const float* __restrict__ w2,
    const float* __restrict__ b2v,
    const float* __restrict__ mu_a, const float* __restrict__ rs_a,
    float* __restrict__ scores)
{
    __shared__ __align__(16) bf16_t sWh[512*32];
    __shared__ __align__(16) bf16_t sWl[512*32];
    __shared__ __align__(16) bf16_t sXh[64*32];
    __shared__ __align__(16) bf16_t sXl[64*32];
    __shared__ float sred[4*64];

    const int tid    = threadIdx.x;
    const int lane   = tid & 63;
    const int wv     = tid >> 6;
    const int token0 = blockIdx.x * TM;

    // ---- X staging role: thread -> (token xt, physical 16B block xp) ----
    const int xt  = tid >> 2;
    const int xp  = tid & 3;
    const int xk8 = 8 * (xp ^ ((xt >> 2) & 3));    // global k-octet (swizzled)
    const float x_mu = mu_a[token0 + xt];
    const float x_rs = rs_a[token0 + xt];
    const float x_at = attn[token0 + xt];
    const float* embrow = emb + (size_t)(token0 + xt) * ND;

    // ---- W staging role: lane -> (row-within-16, physical block) ----
    const int wr  = lane >> 2;
    const int wkb = (lane & 3) ^ (lane >> 4);      // global k-octet (swizzled)

    // ---- compute role ----
    const int cn = lane & 15;                      // col within 16 (h), row sel for frags
    const int cq = lane >> 4;                      // k-octet selector / C row quad
    const int fsw = (cq ^ (cn >> 2)) << 3;         // swizzled frag offset (bf16 units)

    f32x4 acc[4][8];
    float spart[16];
#pragma unroll
    for (int i = 0; i < 16; i++) spart[i] = 0.f;

    for (int hh = 0; hh < 2; hh++) {
#pragma unroll
        for (int tt = 0; tt < 4; tt++)
#pragma unroll
            for (int ht = 0; ht < 8; ht++) acc[tt][ht] = (f32x4){0.f, 0.f, 0.f, 0.f};

        for (int kc = 0; kc < ND; kc += KC) {
            __syncthreads();  // prior chunk fully consumed
            // ---- stage X: LN + bf16 hi/lo split, swizzled b128 writes ----
            {
                const float4 e0 = *(const float4*)(embrow + kc + xk8);
                const float4 e1 = *(const float4*)(embrow + kc + xk8 + 4);
                const float4 g0 = *(const float4*)(ln_g + kc + xk8);
                const float4 g1 = *(const float4*)(ln_g + kc + xk8 + 4);
                const float4 c0 = *(const float4*)(ln_b + kc + xk8);
                const float4 c1 = *(const float4*)(ln_b + kc + xk8 + 4);
                const float ev[8] = {e0.x,e0.y,e0.z,e0.w,e1.x,e1.y,e1.z,e1.w};
                const float gv[8] = {g0.x,g0.y,g0.z,g0.w,g1.x,g1.y,g1.z,g1.w};
                const float cv[8] = {c0.x,c0.y,c0.z,c0.w,c1.x,c1.y,c1.z,c1.w};
                bf16x8 hi, lo;
#pragma unroll
                for (int j = 0; j < 8; j++) {
                    const float x = (ev[j] * x_at - x_mu) * x_rs * gv[j] + cv[j];
                    const bf16_t hb = (bf16_t)x;
                    hi[j] = hb;
                    lo[j] = (bf16_t)(x - (float)hb);
                }
                *(bf16x8*)&sXh[xt*32 + xp*8] = hi;
                *(bf16x8*)&sXl[xt*32 + xp*8] = lo;
            }
            // ---- stage W hi/lo via global_load_lds width=16 ----
            {
                const size_t gbase = (size_t)(hh*512 + wv*128 + wr) * ND + kc + 8*wkb;
#pragma unroll
                for (int i = 0; i < 8; i++) {
                    __builtin_amdgcn_global_load_lds(
                        (const __attribute__((address_space(1))) void*)(w1h + gbase + (size_t)i*16*ND),
                        (__attribute__((address_space(3))) void*)&sWh[(wv*128 + i*16)*32],
                        16, 0, 0);
                }
#pragma unroll
                for (int i = 0; i < 8; i++) {
                    __builtin_amdgcn_global_load_lds(
                        (const __attribute__((address_space(1))) void*)(w1l + gbase + (size_t)i*16*ND),
                        (__attribute__((address_space(3))) void*)&sWl[(wv*128 + i*16)*32],
                        16, 0, 0);
                }
            }
            __syncthreads();  // staged data visible
            // ---- MFMA: 4 t-tiles x 8 h-tiles x 3 products ----
            bf16x8 ah[4], al[4];
#pragma unroll
            for (int tt = 0; tt < 4; tt++) {
                const int off = (tt*16 + cn)*32 + fsw;
                ah[tt] = *(const bf16x8*)&sXh[off];
                al[tt] = *(const bf16x8*)&sXl[off];
            }
#pragma unroll
            for (int ht = 0; ht < 8; ht++) {
                const int off = (wv*128 + ht*16 + cn)*32 + fsw;
                const bf16x8 bh = *(const bf16x8*)&sWh[off];
                const bf16x8 bl = *(const bf16x8*)&sWl[off];
#pragma unroll
                for (int tt = 0; tt < 4; tt++) {
                    acc[tt][ht] = __builtin_amdgcn_mfma_f32_16x16x32_bf16(ah[tt], bh, acc[tt][ht], 0, 0, 0);
                    acc[tt][ht] = __builtin_amdgcn_mfma_f32_16x16x32_bf16(al[tt], bh, acc[tt][ht], 0, 0, 0);
                    acc[tt][ht] = __builtin_amdgcn_mfma_f32_16x16x32_bf16(ah[tt], bl, acc[tt][ht], 0, 0, 0);
                }
            }
        }
        // ---- epilogue for this H-half: bias + gelu + w2 partial reduce ----
#pragma unroll
        for (int ht = 0; ht < 8; ht++) {
            const int hg = hh*512 + wv*128 + ht*16 + cn;
            const float b1v = b1[hg];
            const float w2v = w2[hg];
#pragma unroll
            for (int tt = 0; tt < 4; tt++)
#pragma unroll
                for (int r = 0; r < 4; r++) {
                    const float pre = acc[tt][ht][r] + b1v;
                    const float ge  = 0.5f * pre * (1.0f + erff(pre * 0.70710678118654752f));
                    spart[tt*4 + r] += ge * w2v;
                }
        }
    }
    // reduce the 16 h-lanes (same C row) per value
#pragma unroll
    for (int i = 0; i < 16; i++) {
        float s = spart[i];
        s += __shfl_xor(s, 1, 64);
        s += __shfl_xor(s, 2, 64);
        s += __shfl_xor(s, 4, 64);
        s += __shfl_xor(s, 8, 64);
        spart[i] = s;
    }
    if (cn == 0) {
#pragma unroll
        for (int tt = 0; tt < 4; tt++)
#pragma unroll
            for (int r = 0; r < 4; r++)
                sred[wv*64 + tt*16 + cq*4 + r] = spart[tt*4 + r];
    }
    __syncthreads();
    if (tid < TM) {
        scores[token0 + tid] = sred[tid] + sred[64 + tid] + sred[128 + tid] + sred[192 + tid] + b2v[0];
    }
}

// ---------------------------------------------------------------------------
// Kernel C: entmax1.5 (fp64 bisection for tau) + Kumaraswamy gate (fp64).
// ---------------------------------------------------------------------------
static __device__ __forceinline__ double softplus_d(double x) {
    return (x > 30.0) ? x : log1p(exp(x));
}

__global__ __launch_bounds__(1024) void k_entgate(
    const float* __restrict__ scores, const float* __restrict__ attn,
    const float* __restrict__ u, float* __restrict__ out)
{
    const int b    = blockIdx.x;
    const int tid  = threadIdx.x;
    const int lane = tid & 63;
    const int wid  = tid >> 6;

    __shared__ double redd[16];
    __shared__ double bcd;
    __shared__ float  redf[16];
    __shared__ float  bcf;

    float sm[4], at[4], vv[4];
#pragma unroll
    for (int j = 0; j < 4; j++) {
        const int i = tid + 1024 * j;
        at[j] = attn[b * NS + i];
        const float s = scores[b * NS + i];
        sm[j] = (at[j] == 0.0f) ? -1e9f : s;
        vv[j] = sm[j] * 0.5f;
    }

    float mx = fmaxf(fmaxf(vv[0], vv[1]), fmaxf(vv[2], vv[3]));
#pragma unroll
    for (int m = 32; m; m >>= 1) mx = fmaxf(mx, __shfl_xor(mx, m, 64));
    if (lane == 0) redf[wid] = mx;
    __syncthreads();
    if (tid == 0) {
        float t = redf[0];
        for (int i = 1; i < 16; i++) t = fmaxf(t, redf[i]);
        bcf = t;
    }
    __syncthreads();
    const double mxd = (double)bcf;

    double d[4];
#pragma unroll
    for (int j = 0; j < 4; j++) d[j] = (double)vv[j] - mxd;

    double lo = -1.0, hi = 0.0;
    for (int it = 0; it < 44; it++) {
        const double mid = 0.5 * (lo + hi);
        double s = 0.0;
#pragma unroll
        for (int j = 0; j < 4; j++) {
            const double t = d[j] - mid;
            if (t > 0.0) s += t * t;
        }
#pragma unroll
        for (int m = 32; m; m >>= 1) s += __shfl_xor(s, m, 64);
        if (lane == 0) redd[wid] = s;
        __syncthreads();
        if (tid == 0) {
            double t = 0.0;
            for (int i = 0; i < 16; i++) t += redd[i];
            bcd = t;
        }
        __syncthreads();
        if (bcd >= 1.0) lo = mid; else hi = mid;
    }
    const double tau = lo;

    if (b == 0 && tid == 0) out[2 * NTOK] = 0.0f;  // reg

#pragma unroll
    for (int j = 0; j < 4; j++) {
        const int i = tid + 1024 * j;
        const double t  = d[j] - tau;
        const double zz = (t > 0.0) ? t * t : 0.0;
        const float  z  = (float)zz * at[j];

        const double eff  = (double)sm[j] + 2.0 * (2.0 * (double)z - 1.0);
        const double sp_p = softplus_d(eff)  + 1e-6;
        const double sp_n = softplus_d(-eff) + 1e-6;
        const double uc   = fmin(fmax((double)u[b * NS + i], 1e-6), 1.0 - 1e-6);
        const double xk   = pow(1.0 - pow(1.0 - uc, 1.0 / sp_n), 1.0 / sp_p);
        const double y    = -0.1 + 1.2 * xk;
        const double ycl  = fmin(fmax(y, 0.0), 1.0);
        float h = (ycl > 0.5) ? 1.0f : 0.0f;
        h *= at[j];
        const float g = (h - z) + z;

        out[b * NS + i]        = z;
        out[NTOK + b * NS + i] = g;
    }
}

// ---------------------------------------------------------------------------
extern "C" void kernel_launch(void* const* d_in, const int* in_sizes, int n_in,
                              void* d_out, int out_size, void* d_ws, size_t ws_size,
                              hipStream_t stream)
{
    const float* emb  = (const float*)d_in[0];
    const float* attn = (const float*)d_in[1];
    const float* u    = (const float*)d_in[2];
    const float* ln_g = (const float*)d_in[3];
    const float* ln_b = (const float*)d_in[4];
    const float* w1   = (const float*)d_in[5];
    const float* b1   = (const float*)d_in[6];
    const float* w2   = (const float*)d_in[7];
    const float* b2   = (const float*)d_in[8];
    float* out = (float*)d_out;

    float* wsf    = (float*)d_ws;
    float* scores = wsf;
    float* mu     = wsf + NTOK;
    float* rs     = wsf + 2 * NTOK;
    bf16_t* w1h   = (bf16_t*)(wsf + 3 * NTOK);
    bf16_t* w1l   = w1h + (size_t)NH * ND;

    hipLaunchKernelGGL(k_lnstats, dim3(NTOK / 4), dim3(256), 0, stream,
                       emb, attn, mu, rs);
    hipLaunchKernelGGL(k_wsplit, dim3((NH * ND) / 1024), dim3(256), 0, stream,
                       w1, w1h, w1l);
    hipLaunchKernelGGL(k_scorer, dim3(NTOK / TM), dim3(256), 0, stream,
                       emb, attn, ln_g, ln_b, w1h, w1l, b1, w2, b2, mu, rs, scores);
    hipLaunchKernelGGL(k_entgate, dim3(NB), dim3(1024), 0, stream,
                       scores, attn, u, out);
}

// Round 3
// 1531.921 us; speedup vs baseline: 2.7652x; 1.0654x over previous
//
#include <hip/hip_runtime.h>
#include <math.h>

#define NB 32
#define NS 4096
#define ND 768
#define NH 1024
#define NTOK (NB*NS)
#define NKC (ND/32)   // 24 k-chunks

typedef __bf16 bf16_t;
typedef __bf16 bf16x8 __attribute__((ext_vector_type(8)));
typedef float  f32x4  __attribute__((ext_vector_type(4)));

// ---------------------------------------------------------------------------
// Kernel A: LayerNorm statistics. One wave per token, 3x float4 per lane.
// ---------------------------------------------------------------------------
__global__ __launch_bounds__(256) void k_lnstats(
    const float* __restrict__ emb, const float* __restrict__ attn,
    float* __restrict__ mu_o, float* __restrict__ rs_o)
{
    const int token = blockIdx.x * 4 + (threadIdx.x >> 6);
    const int lane  = threadIdx.x & 63;
    const float am  = attn[token];
    const float* row = emb + (size_t)token * ND;

    float e[12];
    {
        const float4 v0 = *(const float4*)(row + lane * 4);
        const float4 v1 = *(const float4*)(row + 256 + lane * 4);
        const float4 v2 = *(const float4*)(row + 512 + lane * 4);
        e[0]=v0.x; e[1]=v0.y; e[2]=v0.z; e[3]=v0.w;
        e[4]=v1.x; e[5]=v1.y; e[6]=v1.z; e[7]=v1.w;
        e[8]=v2.x; e[9]=v2.y; e[10]=v2.z; e[11]=v2.w;
    }
    float s = 0.f;
#pragma unroll
    for (int j = 0; j < 12; j++) { e[j] *= am; s += e[j]; }
#pragma unroll
    for (int m = 32; m; m >>= 1) s += __shfl_xor(s, m, 64);
    const float mu = s * (1.0f / ND);

    float v = 0.f;
#pragma unroll
    for (int j = 0; j < 12; j++) { float d = e[j] - mu; v += d * d; }
#pragma unroll
    for (int m = 32; m; m >>= 1) v += __shfl_xor(v, m, 64);
    v *= (1.0f / ND);

    if (lane == 0) {
        mu_o[token] = mu;
        rs_o[token] = (float)(1.0 / sqrt((double)v + 1e-5));
    }
}

// ---------------------------------------------------------------------------
// Kernel P: split w1 into bf16 hi/lo, re-blocked to the exact LDS image:
//   blocked[(c*64 + h16)*512 + lane*8 .. +8] =
//       W[h16*16 + (lane>>2)][c*32 + 8*((lane&3)^(lane>>4)) .. +8]
// (XOR swizzle pre-applied; scorer stages each 1KB block with ONE
//  global_load_lds whose per-lane addr = base + lane*16, imm-offset per i.)
// ---------------------------------------------------------------------------
__global__ __launch_bounds__(256) void k_wprep(
    const float* __restrict__ w1, bf16_t* __restrict__ whB, bf16_t* __restrict__ wlB)
{
    const int t   = blockIdx.x * 256 + threadIdx.x;   // [0, 24*64*64)
    const int ln  = t & 63;
    const int h16 = (t >> 6) & 63;
    const int c   = t >> 12;
    const int row = h16 * 16 + (ln >> 2);
    const int k0  = c * 32 + 8 * ((ln & 3) ^ (ln >> 4));

    const float4 a = *(const float4*)(w1 + (size_t)row * ND + k0);
    const float4 b = *(const float4*)(w1 + (size_t)row * ND + k0 + 4);
    const float vv[8] = {a.x,a.y,a.z,a.w,b.x,b.y,b.z,b.w};
    bf16x8 hi, lo;
#pragma unroll
    for (int j = 0; j < 8; j++) {
        const bf16_t hj = (bf16_t)vv[j];
        hi[j] = hj;
        lo[j] = (bf16_t)(vv[j] - (float)hj);
    }
    const size_t o = (size_t)t * 8;
    *(bf16x8*)(whB + o) = hi;
    *(bf16x8*)(wlB + o) = lo;
}

// ---------------------------------------------------------------------------
// Kernel B: fused LN + MLP scorer via bf16x3-split MFMA (16x16x32).
// TM=64 tokens/WG, H in two 512-halves, KC=32. W staged from the blocked
// buffer: per wave 8 hi + 8 lo global_load_lds, all sharing one per-lane
// offset (base + i*1024B) -> no per-load address registers, no spills.
// ---------------------------------------------------------------------------
#define TM 64
#define KC 32

__global__ __launch_bounds__(256, 2) void k_scorer(
    const float* __restrict__ emb, const float* __restrict__ attn,
    const float* __restrict__ ln_g, const float* __restrict__ ln_b,
    const bf16_t* __restrict__ whB, const bf16_t* __restrict__ wlB,
    const float* __restrict__ b1, const float* __restrict__ w2,
    const float* __restrict__ b2v,
    const float* __restrict__ mu_a, const float* __restrict__ rs_a,
    float* __restrict__ scores)
{
    __shared__ __align__(16) bf16_t sWh[512*32];
    __shared__ __align__(16) bf16_t sWl[512*32];
    __shared__ __align__(16) bf16_t sXh[64*32];
    __shared__ __align__(16) bf16_t sXl[64*32];
    __shared__ float sred[4*64];

    const int tid    = threadIdx.x;
    const int lane   = tid & 63;
    const int wv     = tid >> 6;
    const int token0 = blockIdx.x * TM;

    // ---- X staging role ----
    const int xt  = tid >> 2;
    const int xp  = tid & 3;
    const int xk8 = 8 * (xp ^ ((xt >> 2) & 3));
    const float x_mu = mu_a[token0 + xt];
    const float x_rs = rs_a[token0 + xt];
    const float x_at = attn[token0 + xt];
    const float* embrow = emb + (size_t)(token0 + xt) * ND;

    // ---- compute role ----
    const int cn  = lane & 15;
    const int cq  = lane >> 4;
    const int fsw = (cq ^ (cn >> 2)) << 3;

    f32x4 acc[4][8];
    float spart[16];
#pragma unroll
    for (int i = 0; i < 16; i++) spart[i] = 0.f;

    for (int hh = 0; hh < 2; hh++) {
#pragma unroll
        for (int tt = 0; tt < 4; tt++)
#pragma unroll
            for (int ht = 0; ht < 8; ht++) acc[tt][ht] = (f32x4){0.f, 0.f, 0.f, 0.f};

        for (int kc = 0; kc < ND; kc += KC) {
            __syncthreads();  // prior chunk fully consumed
            // ---- issue W DMA first (async), overlap with X VALU work ----
            {
                const size_t blk = ((size_t)((kc >> 5) * 64 + hh * 32 + wv * 8)) * 512 + lane * 8;
                const bf16_t* gh = whB + blk;
                const bf16_t* gl = wlB + blk;
#pragma unroll
                for (int i = 0; i < 8; i++)
                    __builtin_amdgcn_global_load_lds(
                        (const __attribute__((address_space(1))) void*)(gh + i * 512),
                        (__attribute__((address_space(3))) void*)&sWh[(wv*128 + i*16)*32],
                        16, 0, 0);
#pragma unroll
                for (int i = 0; i < 8; i++)
                    __builtin_amdgcn_global_load_lds(
                        (const __attribute__((address_space(1))) void*)(gl + i * 512),
                        (__attribute__((address_space(3))) void*)&sWl[(wv*128 + i*16)*32],
                        16, 0, 0);
            }
            // ---- stage X: LN + bf16 hi/lo split ----
            {
                const float4 e0 = *(const float4*)(embrow + kc + xk8);
                const float4 e1 = *(const float4*)(embrow + kc + xk8 + 4);
                const float4 g0 = *(const float4*)(ln_g + kc + xk8);
                const float4 g1 = *(const float4*)(ln_g + kc + xk8 + 4);
                const float4 c0 = *(const float4*)(ln_b + kc + xk8);
                const float4 c1 = *(const float4*)(ln_b + kc + xk8 + 4);
                const float ev[8] = {e0.x,e0.y,e0.z,e0.w,e1.x,e1.y,e1.z,e1.w};
                const float gv[8] = {g0.x,g0.y,g0.z,g0.w,g1.x,g1.y,g1.z,g1.w};
                const float cv[8] = {c0.x,c0.y,c0.z,c0.w,c1.x,c1.y,c1.z,c1.w};
                bf16x8 hi, lo;
#pragma unroll
                for (int j = 0; j < 8; j++) {
                    const float x = (ev[j] * x_at - x_mu) * x_rs * gv[j] + cv[j];
                    const bf16_t hb = (bf16_t)x;
                    hi[j] = hb;
                    lo[j] = (bf16_t)(x - (float)hb);
                }
                *(bf16x8*)&sXh[xt*32 + xp*8] = hi;
                *(bf16x8*)&sXl[xt*32 + xp*8] = lo;
            }
            __syncthreads();  // staged data visible (drains vmcnt+lgkm)
            // ---- MFMA: 4 t-tiles x 8 h-tiles x 3 products ----
            bf16x8 ah[4], al[4];
#pragma unroll
            for (int tt = 0; tt < 4; tt++) {
                const int off = (tt*16 + cn)*32 + fsw;
                ah[tt] = *(const bf16x8*)&sXh[off];
                al[tt] = *(const bf16x8*)&sXl[off];
            }
#pragma unroll
            for (int ht = 0; ht < 8; ht++) {
                const int off = (wv*128 + ht*16 + cn)*32 + fsw;
                const bf16x8 bh = *(const bf16x8*)&sWh[off];
                const bf16x8 bl = *(const bf16x8*)&sWl[off];
#pragma unroll
                for (int tt = 0; tt < 4; tt++) {
                    acc[tt][ht] = __builtin_amdgcn_mfma_f32_16x16x32_bf16(ah[tt], bh, acc[tt][ht], 0, 0, 0);
                    acc[tt][ht] = __builtin_amdgcn_mfma_f32_16x16x32_bf16(al[tt], bh, acc[tt][ht], 0, 0, 0);
                    acc[tt][ht] = __builtin_amdgcn_mfma_f32_16x16x32_bf16(ah[tt], bl, acc[tt][ht], 0, 0, 0);
                }
            }
        }
        // ---- epilogue: bias + exact gelu + w2 partial reduce ----
#pragma unroll
        for (int ht = 0; ht < 8; ht++) {
            const int hg = hh*512 + wv*128 + ht*16 + cn;
            const float b1v = b1[hg];
            const float w2v = w2[hg];
#pragma unroll
            for (int tt = 0; tt < 4; tt++)
#pragma unroll
                for (int r = 0; r < 4; r++) {
                    const float pre = acc[tt][ht][r] + b1v;
                    const float ge  = 0.5f * pre * (1.0f + erff(pre * 0.70710678118654752f));
                    spart[tt*4 + r] += ge * w2v;
                }
        }
    }
#pragma unroll
    for (int i = 0; i < 16; i++) {
        float s = spart[i];
        s += __shfl_xor(s, 1, 64);
        s += __shfl_xor(s, 2, 64);
        s += __shfl_xor(s, 4, 64);
        s += __shfl_xor(s, 8, 64);
        spart[i] = s;
    }
    if (cn == 0) {
#pragma unroll
        for (int tt = 0; tt < 4; tt++)
#pragma unroll
            for (int r = 0; r < 4; r++)
                sred[wv*64 + tt*16 + cq*4 + r] = spart[tt*4 + r];
    }
    __syncthreads();
    if (tid < TM) {
        scores[token0 + tid] = sred[tid] + sred[64 + tid] + sred[128 + tid] + sred[192 + tid] + b2v[0];
    }
}

// ---------------------------------------------------------------------------
// Kernel T: entmax1.5 tau via fp64 bisection. One block per batch row.
// Ping-pong reduction buffers -> 1 barrier per iteration.
// ---------------------------------------------------------------------------
__global__ __launch_bounds__(1024) void k_tau(
    const float* __restrict__ scores, const float* __restrict__ attn,
    double* __restrict__ tau_o, double* __restrict__ mx_o)
{
    const int b    = blockIdx.x;
    const int tid  = threadIdx.x;
    const int lane = tid & 63;
    const int wid  = tid >> 6;

    __shared__ double redd[2][16];
    __shared__ float  redf[16];
    __shared__ float  bcf;

    float vv[4];
#pragma unroll
    for (int j = 0; j < 4; j++) {
        const int i = tid + 1024 * j;
        const float at = attn[b * NS + i];
        const float s  = scores[b * NS + i];
        vv[j] = ((at == 0.0f) ? -1e9f : s) * 0.5f;
    }

    float mx = fmaxf(fmaxf(vv[0], vv[1]), fmaxf(vv[2], vv[3]));
#pragma unroll
    for (int m = 32; m; m >>= 1) mx = fmaxf(mx, __shfl_xor(mx, m, 64));
    if (lane == 0) redf[wid] = mx;
    __syncthreads();
    if (tid == 0) {
        float t = redf[0];
        for (int i = 1; i < 16; i++) t = fmaxf(t, redf[i]);
        bcf = t;
    }
    __syncthreads();
    const double mxd = (double)bcf;

    double d[4];
#pragma unroll
    for (int j = 0; j < 4; j++) d[j] = (double)vv[j] - mxd;

    double lo = -1.0, hi = 0.0;
    for (int it = 0; it < 44; it++) {
        const double mid = 0.5 * (lo + hi);
        double s = 0.0;
#pragma unroll
        for (int j = 0; j < 4; j++) {
            const double t = d[j] - mid;
            if (t > 0.0) s += t * t;
        }
#pragma unroll
        for (int m = 32; m; m >>= 1) s += __shfl_xor(s, m, 64);
        const int p = it & 1;
        if (lane == 0) redd[p][wid] = s;
        __syncthreads();
        double tot = 0.0;
#pragma unroll
        for (int i = 0; i < 16; i++) tot += redd[p][i];
        if (tot >= 1.0) lo = mid; else hi = mid;   // uniform across block
    }
    if (tid == 0) { tau_o[b] = lo; mx_o[b] = mxd; }
}

// ---------------------------------------------------------------------------
// Kernel G: Kumaraswamy gate, grid-wide elementwise (fp64 math).
// ---------------------------------------------------------------------------
static __device__ __forceinline__ double softplus_d(double x) {
    return (x > 30.0) ? x : log1p(exp(x));
}

__global__ __launch_bounds__(256) void k_gate(
    const float* __restrict__ scores, const float* __restrict__ attn,
    const float* __restrict__ u,
    const double* __restrict__ tau_a, const double* __restrict__ mx_a,
    float* __restrict__ out)
{
    const int i0 = (blockIdx.x * 256 + threadIdx.x) * 4;
    const int b  = i0 >> 12;   // 4096 per row
    const double tau = tau_a[b];
    const double mxd = mx_a[b];

    const float4 s4 = *(const float4*)(scores + i0);
    const float4 a4 = *(const float4*)(attn + i0);
    const float4 u4 = *(const float4*)(u + i0);
    const float sv[4] = {s4.x, s4.y, s4.z, s4.w};
    const float av[4] = {a4.x, a4.y, a4.z, a4.w};
    const float uv[4] = {u4.x, u4.y, u4.z, u4.w};

    float zo[4], go[4];
#pragma unroll
    for (int j = 0; j < 4; j++) {
        const float at = av[j];
        const float sm = (at == 0.0f) ? -1e9f : sv[j];
        const float vvf = sm * 0.5f;
        const double dd = (double)vvf - mxd;
        const double t  = dd - tau;
        const double zz = (t > 0.0) ? t * t : 0.0;
        const float  z  = (float)zz * at;

        const double eff  = (double)sm + 2.0 * (2.0 * (double)z - 1.0);
        const double sp_p = softplus_d(eff)  + 1e-6;
        const double sp_n = softplus_d(-eff) + 1e-6;
        const double uc   = fmin(fmax((double)uv[j], 1e-6), 1.0 - 1e-6);
        const double xk   = pow(1.0 - pow(1.0 - uc, 1.0 / sp_n), 1.0 / sp_p);
        const double y    = -0.1 + 1.2 * xk;
        const double ycl  = fmin(fmax(y, 0.0), 1.0);
        float h = (ycl > 0.5) ? 1.0f : 0.0f;
        h *= at;
        zo[j] = z;
        go[j] = (h - z) + z;
    }
    *(float4*)(out + i0)        = (float4){zo[0], zo[1], zo[2], zo[3]};
    *(float4*)(out + NTOK + i0) = (float4){go[0], go[1], go[2], go[3]};
    if (i0 == 0) out[2 * NTOK] = 0.0f;   // reg
}

// ---------------------------------------------------------------------------
extern "C" void kernel_launch(void* const* d_in, const int* in_sizes, int n_in,
                              void* d_out, int out_size, void* d_ws, size_t ws_size,
                              hipStream_t stream)
{
    const float* emb  = (const float*)d_in[0];
    const float* attn = (const float*)d_in[1];
    const float* u    = (const float*)d_in[2];
    const float* ln_g = (const float*)d_in[3];
    const float* ln_b = (const float*)d_in[4];
    const float* w1   = (const float*)d_in[5];
    const float* b1   = (const float*)d_in[6];
    const float* w2   = (const float*)d_in[7];
    const float* b2   = (const float*)d_in[8];
    float* out = (float*)d_out;

    float*  wsf    = (float*)d_ws;
    float*  scores = wsf;                       // NTOK
    float*  mu     = wsf + NTOK;                // NTOK
    float*  rs     = wsf + 2 * NTOK;            // NTOK
    double* taud   = (double*)(wsf + 3 * NTOK); // NB doubles (8B aligned: 3*NTOK*4 % 8 == 0)
    double* mxd    = taud + NB;
    bf16_t* w1hB   = (bf16_t*)(mxd + NB);       // NH*ND bf16 (blocked)
    bf16_t* w1lB   = w1hB + (size_t)NH * ND;

    hipLaunchKernelGGL(k_lnstats, dim3(NTOK / 4), dim3(256), 0, stream,
                       emb, attn, mu, rs);
    hipLaunchKernelGGL(k_wprep, dim3((NKC * 64 * 64) / 256), dim3(256), 0, stream,
                       w1, w1hB, w1lB);
    hipLaunchKernelGGL(k_scorer, dim3(NTOK / TM), dim3(256), 0, stream,
                       emb, attn, ln_g, ln_b, w1hB, w1lB, b1, w2, b2, mu, rs, scores);
    hipLaunchKernelGGL(k_tau, dim3(NB), dim3(1024), 0, stream,
                       scores, attn, taud, mxd);
    hipLaunchKernelGGL(k_gate, dim3(NTOK / 1024), dim3(256), 0, stream,
                       scores, attn, u, taud, mxd, out);
}

// Round 4
// 1361.776 us; speedup vs baseline: 3.1106x; 1.1249x over previous
//
#include <hip/hip_runtime.h>
#include <math.h>

#define NB 32
#define NS 4096
#define ND 768
#define NH 1024
#define NTOK (NB*NS)
#define NKC (ND/32)   // 24 k-chunks

typedef __bf16 bf16_t;
typedef __bf16 bf16x8 __attribute__((ext_vector_type(8)));
typedef float  f32x4  __attribute__((ext_vector_type(4)));

// ---------------------------------------------------------------------------
// Kernel A: LayerNorm statistics. One wave per token, 3x float4 per lane.
// ---------------------------------------------------------------------------
__global__ __launch_bounds__(256) void k_lnstats(
    const float* __restrict__ emb, const float* __restrict__ attn,
    float* __restrict__ mu_o, float* __restrict__ rs_o)
{
    const int token = blockIdx.x * 4 + (threadIdx.x >> 6);
    const int lane  = threadIdx.x & 63;
    const float am  = attn[token];
    const float* row = emb + (size_t)token * ND;

    float e[12];
    {
        const float4 v0 = *(const float4*)(row + lane * 4);
        const float4 v1 = *(const float4*)(row + 256 + lane * 4);
        const float4 v2 = *(const float4*)(row + 512 + lane * 4);
        e[0]=v0.x; e[1]=v0.y; e[2]=v0.z; e[3]=v0.w;
        e[4]=v1.x; e[5]=v1.y; e[6]=v1.z; e[7]=v1.w;
        e[8]=v2.x; e[9]=v2.y; e[10]=v2.z; e[11]=v2.w;
    }
    float s = 0.f;
#pragma unroll
    for (int j = 0; j < 12; j++) { e[j] *= am; s += e[j]; }
#pragma unroll
    for (int m = 32; m; m >>= 1) s += __shfl_xor(s, m, 64);
    const float mu = s * (1.0f / ND);

    float v = 0.f;
#pragma unroll
    for (int j = 0; j < 12; j++) { float d = e[j] - mu; v += d * d; }
#pragma unroll
    for (int m = 32; m; m >>= 1) v += __shfl_xor(v, m, 64);
    v *= (1.0f / ND);

    if (lane == 0) {
        mu_o[token] = mu;
        rs_o[token] = (float)(1.0 / sqrt((double)v + 1e-5));
    }
}

// ---------------------------------------------------------------------------
// Kernel P: split w1 into bf16 hi/lo, re-blocked to the exact LDS image
// (XOR swizzle pre-applied). Block index: [(c*64 + h16)*512 + lane*8].
// ---------------------------------------------------------------------------
__global__ __launch_bounds__(256) void k_wprep(
    const float* __restrict__ w1, bf16_t* __restrict__ whB, bf16_t* __restrict__ wlB)
{
    const int t   = blockIdx.x * 256 + threadIdx.x;   // [0, 24*64*64)
    const int ln  = t & 63;
    const int h16 = (t >> 6) & 63;
    const int c   = t >> 12;
    const int row = h16 * 16 + (ln >> 2);
    const int k0  = c * 32 + 8 * ((ln & 3) ^ (ln >> 4));

    const float4 a = *(const float4*)(w1 + (size_t)row * ND + k0);
    const float4 b = *(const float4*)(w1 + (size_t)row * ND + k0 + 4);
    const float vv[8] = {a.x,a.y,a.z,a.w,b.x,b.y,b.z,b.w};
    bf16x8 hi, lo;
#pragma unroll
    for (int j = 0; j < 8; j++) {
        const bf16_t hj = (bf16_t)vv[j];
        hi[j] = hj;
        lo[j] = (bf16_t)(vv[j] - (float)hj);
    }
    const size_t o = (size_t)t * 8;
    *(bf16x8*)(whB + o) = hi;
    *(bf16x8*)(wlB + o) = lo;
}

// ---------------------------------------------------------------------------
// Kernel B: fused LN + MLP scorer via bf16x3-split MFMA (16x16x32).
// TM=64 tokens/WG, H in FOUR 256-quarters (acc = 64 AGPRs -> ~192 arch VGPRs
// available, kills the 7-dword/iter scratch spill measured in r2/r3).
// W staged from blocked buffer via global_load_lds (1 per-lane offset, imm
// strides). X staged through VGPRs with LN + bf16 hi/lo split fused.
// LDS: Wh 16K + Wl 16K + Xh 4K + Xl 4K + sred 1K = 41 KB.
// ---------------------------------------------------------------------------
#define TM 64
#define KC 32

__global__ __launch_bounds__(256, 2) void k_scorer(
    const float* __restrict__ emb, const float* __restrict__ attn,
    const float* __restrict__ ln_g, const float* __restrict__ ln_b,
    const bf16_t* __restrict__ whB, const bf16_t* __restrict__ wlB,
    const float* __restrict__ b1, const float* __restrict__ w2,
    const float* __restrict__ b2v,
    const float* __restrict__ mu_a, const float* __restrict__ rs_a,
    float* __restrict__ scores)
{
    __shared__ __align__(16) bf16_t sWh[256*32];
    __shared__ __align__(16) bf16_t sWl[256*32];
    __shared__ __align__(16) bf16_t sXh[64*32];
    __shared__ __align__(16) bf16_t sXl[64*32];
    __shared__ float sred[4*64];

    const int tid    = threadIdx.x;
    const int lane   = tid & 63;
    const int wv     = tid >> 6;
    const int token0 = blockIdx.x * TM;

    // ---- X staging role ----
    const int xt  = tid >> 2;
    const int xp  = tid & 3;
    const int xk8 = 8 * (xp ^ ((xt >> 2) & 3));
    const float x_mu = mu_a[token0 + xt];
    const float x_rs = rs_a[token0 + xt];
    const float x_at = attn[token0 + xt];
    const float* embrow = emb + (size_t)(token0 + xt) * ND;

    // ---- compute role ----
    const int cn  = lane & 15;
    const int cq  = lane >> 4;
    const int fsw = (cq ^ (cn >> 2)) << 3;

    f32x4 acc[4][4];
    float spart[16];
#pragma unroll
    for (int i = 0; i < 16; i++) spart[i] = 0.f;

    for (int hq = 0; hq < 4; hq++) {
#pragma unroll
        for (int tt = 0; tt < 4; tt++)
#pragma unroll
            for (int ht = 0; ht < 4; ht++) acc[tt][ht] = (f32x4){0.f, 0.f, 0.f, 0.f};

        for (int kc = 0; kc < ND; kc += KC) {
            __syncthreads();  // prior chunk fully consumed
            // ---- issue W DMA first (async), overlap with X VALU work ----
            {
                const size_t blk = ((size_t)((kc >> 5) * 64 + hq * 16 + wv * 4)) * 512 + lane * 8;
                const bf16_t* gh = whB + blk;
                const bf16_t* gl = wlB + blk;
#pragma unroll
                for (int i = 0; i < 4; i++)
                    __builtin_amdgcn_global_load_lds(
                        (const __attribute__((address_space(1))) void*)(gh + i * 512),
                        (__attribute__((address_space(3))) void*)&sWh[(wv*64 + i*16)*32],
                        16, 0, 0);
#pragma unroll
                for (int i = 0; i < 4; i++)
                    __builtin_amdgcn_global_load_lds(
                        (const __attribute__((address_space(1))) void*)(gl + i * 512),
                        (__attribute__((address_space(3))) void*)&sWl[(wv*64 + i*16)*32],
                        16, 0, 0);
            }
            // ---- stage X: LN + bf16 hi/lo split ----
            {
                const float4 e0 = *(const float4*)(embrow + kc + xk8);
                const float4 e1 = *(const float4*)(embrow + kc + xk8 + 4);
                const float4 g0 = *(const float4*)(ln_g + kc + xk8);
                const float4 g1 = *(const float4*)(ln_g + kc + xk8 + 4);
                const float4 c0 = *(const float4*)(ln_b + kc + xk8);
                const float4 c1 = *(const float4*)(ln_b + kc + xk8 + 4);
                const float ev[8] = {e0.x,e0.y,e0.z,e0.w,e1.x,e1.y,e1.z,e1.w};
                const float gv[8] = {g0.x,g0.y,g0.z,g0.w,g1.x,g1.y,g1.z,g1.w};
                const float cv[8] = {c0.x,c0.y,c0.z,c0.w,c1.x,c1.y,c1.z,c1.w};
                bf16x8 hi, lo;
#pragma unroll
                for (int j = 0; j < 8; j++) {
                    const float x = (ev[j] * x_at - x_mu) * x_rs * gv[j] + cv[j];
                    const bf16_t hb = (bf16_t)x;
                    hi[j] = hb;
                    lo[j] = (bf16_t)(x - (float)hb);
                }
                *(bf16x8*)&sXh[xt*32 + xp*8] = hi;
                *(bf16x8*)&sXl[xt*32 + xp*8] = lo;
            }
            __syncthreads();  // staged data visible (drains vmcnt+lgkm)
            // ---- MFMA: 4 t-tiles x 4 h-tiles x 3 products ----
            bf16x8 ah[4], al[4];
#pragma unroll
            for (int tt = 0; tt < 4; tt++) {
                const int off = (tt*16 + cn)*32 + fsw;
                ah[tt] = *(const bf16x8*)&sXh[off];
                al[tt] = *(const bf16x8*)&sXl[off];
            }
#pragma unroll
            for (int ht = 0; ht < 4; ht++) {
                const int off = (wv*64 + ht*16 + cn)*32 + fsw;
                const bf16x8 bh = *(const bf16x8*)&sWh[off];
                const bf16x8 bl = *(const bf16x8*)&sWl[off];
#pragma unroll
                for (int tt = 0; tt < 4; tt++) {
                    acc[tt][ht] = __builtin_amdgcn_mfma_f32_16x16x32_bf16(ah[tt], bh, acc[tt][ht], 0, 0, 0);
                    acc[tt][ht] = __builtin_amdgcn_mfma_f32_16x16x32_bf16(al[tt], bh, acc[tt][ht], 0, 0, 0);
                    acc[tt][ht] = __builtin_amdgcn_mfma_f32_16x16x32_bf16(ah[tt], bl, acc[tt][ht], 0, 0, 0);
                }
            }
        }
        // ---- epilogue for this quarter: bias + exact gelu + w2 reduce ----
#pragma unroll
        for (int ht = 0; ht < 4; ht++) {
            const int hg = hq*256 + wv*64 + ht*16 + cn;
            const float b1v = b1[hg];
            const float w2v = w2[hg];
#pragma unroll
            for (int tt = 0; tt < 4; tt++)
#pragma unroll
                for (int r = 0; r < 4; r++) {
                    const float pre = acc[tt][ht][r] + b1v;
                    const float ge  = 0.5f * pre * (1.0f + erff(pre * 0.70710678118654752f));
                    spart[tt*4 + r] += ge * w2v;
                }
        }
    }
#pragma unroll
    for (int i = 0; i < 16; i++) {
        float s = spart[i];
        s += __shfl_xor(s, 1, 64);
        s += __shfl_xor(s, 2, 64);
        s += __shfl_xor(s, 4, 64);
        s += __shfl_xor(s, 8, 64);
        spart[i] = s;
    }
    if (cn == 0) {
#pragma unroll
        for (int tt = 0; tt < 4; tt++)
#pragma unroll
            for (int r = 0; r < 4; r++)
                sred[wv*64 + tt*16 + cq*4 + r] = spart[tt*4 + r];
    }
    __syncthreads();
    if (tid < TM) {
        scores[token0 + tid] = sred[tid] + sred[64 + tid] + sred[128 + tid] + sred[192 + tid] + b2v[0];
    }
}

// ---------------------------------------------------------------------------
// Kernel TG: entmax1.5 tau (fp64 bisection) + Kumaraswamy gate, fused.
// One 1024-thread block per batch row. tau is block-uniform in registers.
// ---------------------------------------------------------------------------
static __device__ __forceinline__ double softplus_d(double x) {
    return (x > 30.0) ? x : log1p(exp(x));
}

__global__ __launch_bounds__(1024) void k_taugate(
    const float* __restrict__ scores, const float* __restrict__ attn,
    const float* __restrict__ u, float* __restrict__ out)
{
    const int b    = blockIdx.x;
    const int tid  = threadIdx.x;
    const int lane = tid & 63;
    const int wid  = tid >> 6;

    __shared__ double redd[2][16];
    __shared__ float  redf[16];
    __shared__ float  bcf;

    float vv[4], at[4], sm[4];
#pragma unroll
    for (int j = 0; j < 4; j++) {
        const int i = tid + 1024 * j;
        at[j] = attn[b * NS + i];
        const float s = scores[b * NS + i];
        sm[j] = (at[j] == 0.0f) ? -1e9f : s;
        vv[j] = sm[j] * 0.5f;
    }

    float mx = fmaxf(fmaxf(vv[0], vv[1]), fmaxf(vv[2], vv[3]));
#pragma unroll
    for (int m = 32; m; m >>= 1) mx = fmaxf(mx, __shfl_xor(mx, m, 64));
    if (lane == 0) redf[wid] = mx;
    __syncthreads();
    if (tid == 0) {
        float t = redf[0];
        for (int i = 1; i < 16; i++) t = fmaxf(t, redf[i]);
        bcf = t;
    }
    __syncthreads();
    const double mxd = (double)bcf;

    double d[4];
#pragma unroll
    for (int j = 0; j < 4; j++) d[j] = (double)vv[j] - mxd;

    double lo = -1.0, hi = 0.0;
    for (int it = 0; it < 44; it++) {
        const double mid = 0.5 * (lo + hi);
        double s = 0.0;
#pragma unroll
        for (int j = 0; j < 4; j++) {
            const double t = d[j] - mid;
            if (t > 0.0) s += t * t;
        }
#pragma unroll
        for (int m = 32; m; m >>= 1) s += __shfl_xor(s, m, 64);
        const int p = it & 1;
        if (lane == 0) redd[p][wid] = s;
        __syncthreads();
        double tot = 0.0;
#pragma unroll
        for (int i = 0; i < 16; i++) tot += redd[p][i];
        if (tot >= 1.0) lo = mid; else hi = mid;   // uniform across block
    }
    const double tau = lo;

    if (b == 0 && tid == 0) out[2 * NTOK] = 0.0f;  // reg

#pragma unroll
    for (int j = 0; j < 4; j++) {
        const int i = tid + 1024 * j;
        const double t  = d[j] - tau;
        const double zz = (t > 0.0) ? t * t : 0.0;
        const float  z  = (float)zz * at[j];

        const double eff  = (double)sm[j] + 2.0 * (2.0 * (double)z - 1.0);
        const double sp_p = softplus_d(eff)  + 1e-6;
        const double sp_n = softplus_d(-eff) + 1e-6;
        const double uc   = fmin(fmax((double)u[b * NS + i], 1e-6), 1.0 - 1e-6);
        const double xk   = pow(1.0 - pow(1.0 - uc, 1.0 / sp_n), 1.0 / sp_p);
        const double y    = -0.1 + 1.2 * xk;
        const double ycl  = fmin(fmax(y, 0.0), 1.0);
        float h = (ycl > 0.5) ? 1.0f : 0.0f;
        h *= at[j];
        const float g = (h - z) + z;

        out[b * NS + i]        = z;
        out[NTOK + b * NS + i] = g;
    }
}

// ---------------------------------------------------------------------------
extern "C" void kernel_launch(void* const* d_in, const int* in_sizes, int n_in,
                              void* d_out, int out_size, void* d_ws, size_t ws_size,
                              hipStream_t stream)
{
    const float* emb  = (const float*)d_in[0];
    const float* attn = (const float*)d_in[1];
    const float* u    = (const float*)d_in[2];
    const float* ln_g = (const float*)d_in[3];
    const float* ln_b = (const float*)d_in[4];
    const float* w1   = (const float*)d_in[5];
    const float* b1   = (const float*)d_in[6];
    const float* w2   = (const float*)d_in[7];
    const float* b2   = (const float*)d_in[8];
    float* out = (float*)d_out;

    float*  wsf    = (float*)d_ws;
    float*  scores = wsf;                       // NTOK
    float*  mu     = wsf + NTOK;                // NTOK
    float*  rs     = wsf + 2 * NTOK;            // NTOK
    bf16_t* w1hB   = (bf16_t*)(wsf + 3 * NTOK); // NH*ND bf16 (blocked)
    bf16_t* w1lB   = w1hB + (size_t)NH * ND;

    hipLaunchKernelGGL(k_lnstats, dim3(NTOK / 4), dim3(256), 0, stream,
                       emb, attn, mu, rs);
    hipLaunchKernelGGL(k_wprep, dim3((NKC * 64 * 64) / 256), dim3(256), 0, stream,
                       w1, w1hB, w1lB);
    hipLaunchKernelGGL(k_scorer, dim3(NTOK / TM), dim3(256), 0, stream,
                       emb, attn, ln_g, ln_b, w1hB, w1lB, b1, w2, b2, mu, rs, scores);
    hipLaunchKernelGGL(k_taugate, dim3(NB), dim3(1024), 0, stream,
                       scores, attn, u, out);
}